// Round 15
// baseline (555.133 us; speedup 1.0000x reference)
//
#include <hip/hip_runtime.h>
#include <stdint.h>

// N=64, D=128, EMB=64, OUTG=64, A=512, B=256, G=8
// group_mask[i,j] = (j//2 == i).
//
// k_f3: fully fused f-MLP per (b,g) block, 512 thr / 8 waves, 80 KB LDS.
// ROUND 15: __launch_bounds__(512, 3) -> 170-reg total budget, 3 waves/SIMD
// (round 11's (512,2) ran 2 waves/SIMD at 22% occupancy, both pipes ~34% busy;
// rounds 12/13/14 alternatives all regressed and were reverted).
// Register model (calibrated r8-r14): budget = 512 / min_waves TOTAL regs
// (arch + acc unified on gfx950); VGPR_Count reports the arch portion.
//   stage emb_s[b]+wadj -> aggr fp32 -> packed A0 frags (LDS)
//   2 super-chunks of 256 h0-cols:
//     barrier -> per-(nt2,mt): layer0 MFMA (K=64) + base_f/leaky -> h0
//     two-plane f16 hi/lo LDS (granule-XOR swz) -> barrier ->
//     8 barrier-free layer1 K-steps (fw1 frags from L2, acc1[4][4])
//   epilogue: +fb1/leaky -> fused layer2 partial dots -> LDS reduce -> out.
// fp16-split x3 MFMA: a = a_hi+a_lo; a*b ~= AhBh + AhBl + AlBh (fp32 acc).

typedef _Float16 half8 __attribute__((ext_vector_type(8)));
typedef float    f32x4 __attribute__((ext_vector_type(4)));
typedef uint32_t u32x4 __attribute__((ext_vector_type(4)));

#define MFMA16(a, b, c) __builtin_amdgcn_mfma_f32_16x16x32_f16(a, b, c, 0, 0, 0)

__device__ __forceinline__ float leaky(float v) { return v >= 0.f ? v : 0.01f * v; }

__device__ __forceinline__ uint32_t packsplit(float v) {
    _Float16 hi = (_Float16)v;
    _Float16 lo = (_Float16)(v - (float)hi);
    union { _Float16 f; unsigned short u; } a, c;
    a.f = hi; c.f = lo;
    return (uint32_t)a.u | ((uint32_t)c.u << 16);
}

__device__ __forceinline__ void unpackA(u32x4 w0, u32x4 w1, half8& Ah, half8& Al) {
    union { u32x4 u; half8 h; } ah, al;
    ah.u[0] = (w0[0] & 0xffffu) | (w0[1] << 16);
    ah.u[1] = (w0[2] & 0xffffu) | (w0[3] << 16);
    ah.u[2] = (w1[0] & 0xffffu) | (w1[1] << 16);
    ah.u[3] = (w1[2] & 0xffffu) | (w1[3] << 16);
    al.u[0] = (w0[0] >> 16) | (w0[1] & 0xffff0000u);
    al.u[1] = (w0[2] >> 16) | (w0[3] & 0xffff0000u);
    al.u[2] = (w1[0] >> 16) | (w1[1] & 0xffff0000u);
    al.u[3] = (w1[2] >> 16) | (w1[3] & 0xffff0000u);
    Ah = ah.h; Al = al.h;
}

// ---------------- prep kernels ----------------

__global__ void k_base(const float* __restrict__ emb,
                       const float* __restrict__ gw0, const float* __restrict__ gb0,
                       const float* __restrict__ fw0, const float* __restrict__ fb0,
                       float* __restrict__ base_g, float* __restrict__ base_f)
{
    int blk = blockIdx.x;            // 256 blocks
    int n     = blk >> 2;
    int half  = (blk >> 1) & 1;
    int which = blk & 1;
    int c = half * 256 + threadIdx.x;
    const float* W    = which ? fw0 : gw0;
    const float* bias = which ? fb0 : gb0;
    float* dst        = which ? base_f : base_g;
    int off           = which ? 64 : 128;
    const float* e = emb + n * 64;
    float acc = bias[c];
    #pragma unroll 8
    for (int k = 0; k < 64; ++k)
        acc = fmaf(e[k], W[(off + k) * 512 + c], acc);
    dst[n * 512 + c] = acc;
}

// w2P[node][a][d] = fw2[a][2*node+d]
__global__ void k_w2p(const float* __restrict__ fw2, float* __restrict__ w2P)
{
    int tid = blockIdx.x * 256 + threadIdx.x;   // grid 256 -> 65536
    int c = tid >> 9, a = tid & 511;            // c = 2*node+d
    int node = c >> 1, d = c & 1;
    w2P[(node * 512 + a) * 2 + d] = fw2[a * 128 + c];
}

// Fragment-linear f16 hi/lo splits (B-operand layout for mfma 16x16x32):
//  fw1/gw1 (512x512): frag[(kstep*32+ntg)*64+l][j] = W[kstep*32+(l>>4)*8+j][ntg*16+(l&15)]
//  fw0 rows 0..63:    frag[(kstep*32+ntg)*64+l][j] (kstep 0..1)
//  gw2 (512x64):      frag[(kstep*4+ntg)*64+l][j]
__global__ void k_splitw(const float* __restrict__ fw0, const float* __restrict__ fw1,
                         const float* __restrict__ gw1, const float* __restrict__ gw2,
                         _Float16* __restrict__ fw0h, _Float16* __restrict__ fw0l,
                         _Float16* __restrict__ fw1h, _Float16* __restrict__ fw1l,
                         _Float16* __restrict__ gw1h, _Float16* __restrict__ gw1l,
                         _Float16* __restrict__ gw2h, _Float16* __restrict__ gw2l)
{
    int tid = blockIdx.x * 256 + threadIdx.x;
    if (blockIdx.x < 128) {                       // fw1
        int l = tid & 63, grp = tid >> 6;
        int kstep = grp >> 5, ntg = grp & 31;
        #pragma unroll
        for (int j = 0; j < 8; ++j) {
            int k = kstep * 32 + (l >> 4) * 8 + j;
            int n = ntg * 16 + (l & 15);
            float v = fw1[k * 512 + n];
            _Float16 h = (_Float16)v;
            fw1h[tid * 8 + j] = h;
            fw1l[tid * 8 + j] = (_Float16)(v - (float)h);
        }
    } else if (blockIdx.x < 144) {                // fw0 rows 0..63
        int t2 = tid - 32768;
        int l = t2 & 63, grp = t2 >> 6;
        int kstep = grp >> 5, ntg = grp & 31;
        #pragma unroll
        for (int j = 0; j < 8; ++j) {
            int k = kstep * 32 + (l >> 4) * 8 + j;
            int n = ntg * 16 + (l & 15);
            float v = fw0[k * 512 + n];
            _Float16 h = (_Float16)v;
            fw0h[t2 * 8 + j] = h;
            fw0l[t2 * 8 + j] = (_Float16)(v - (float)h);
        }
    } else if (blockIdx.x < 272) {                // gw1
        int t4 = tid - 36864;
        int l = t4 & 63, grp = t4 >> 6;
        int kstep = grp >> 5, ntg = grp & 31;
        #pragma unroll
        for (int j = 0; j < 8; ++j) {
            int k = kstep * 32 + (l >> 4) * 8 + j;
            int n = ntg * 16 + (l & 15);
            float v = gw1[k * 512 + n];
            _Float16 h = (_Float16)v;
            gw1h[t4 * 8 + j] = h;
            gw1l[t4 * 8 + j] = (_Float16)(v - (float)h);
        }
    } else {                                      // gw2
        int t3 = tid - 69632;                     // 0..4095
        int l = t3 & 63, grp = t3 >> 6;           // grp 0..63
        int kstep = grp >> 2, ntg = grp & 3;
        #pragma unroll
        for (int j = 0; j < 8; ++j) {
            int k = kstep * 32 + (l >> 4) * 8 + j;
            int n = ntg * 16 + (l & 15);
            float v = gw2[k * 64 + n];
            _Float16 h = (_Float16)v;
            gw2h[t3 * 8 + j] = h;
            gw2l[t3 * 8 + j] = (_Float16)(v - (float)h);
        }
    }
}

// ---------------- k_gmlp: g-MLP on MFMA (unchanged) ----------------

__global__ __launch_bounds__(512, 2) void k_gmlp(
    const float* __restrict__ samples, const float* __restrict__ gw0,
    const float* __restrict__ base_g, const float* __restrict__ gb1,
    const float* __restrict__ gb2,
    const _Float16* __restrict__ gw1h, const _Float16* __restrict__ gw1l,
    const _Float16* __restrict__ gw2h, const _Float16* __restrict__ gw2l,
    float* __restrict__ emb_s)
{
    __shared__ __align__(16) unsigned char smem[81920];
    const int t = threadIdx.x, l = t & 63, wv = t >> 6;
    const int q = l >> 4, lr = l & 15;
    const int b = blockIdx.x;

    f32x4 zero4 = {0.f, 0.f, 0.f, 0.f};
    f32x4 acc[4][4];
    #pragma unroll
    for (int mt = 0; mt < 4; ++mt)
        #pragma unroll
        for (int nt = 0; nt < 4; ++nt) acc[mt][nt] = zero4;

    auto stage = [&](int kk, int bq) {
        #pragma unroll
        for (int it = 0; it < 4; ++it) {
            int n = it * 16 + (t >> 5);
            int c = kk * 32 + (t & 31);
            float s0 = samples[b * 128 + 2 * n];
            float s1 = samples[b * 128 + 2 * n + 1];
            float v = fmaf(s0, gw0[(2 * n) * 512 + c],
                      fmaf(s1, gw0[(2 * n + 1) * 512 + c], base_g[n * 512 + c]));
            v = leaky(v);
            int kl = t & 31;
            int sw = (((kl >> 2) ^ (n & 7)) << 2) | (kl & 3);
            *(uint32_t*)(smem + bq * 8192 + n * 128 + sw * 4) = packsplit(v);
        }
    };

    stage(0, 0);
    for (int kk = 0; kk < 16; ++kk) {
        const int pb = kk & 1;
        __syncthreads();
        if (kk < 15) stage(kk + 1, pb ^ 1);

        half8 Ah[4], Al[4];
        #pragma unroll
        for (int mt = 0; mt < 4; ++mt) {
            int row = mt * 16 + lr, f = row & 7;
            const unsigned char* rb = smem + pb * 8192 + row * 128;
            u32x4 w0 = *(const u32x4*)(rb + (((2 * q) ^ f) << 4));
            u32x4 w1 = *(const u32x4*)(rb + (((2 * q + 1) ^ f) << 4));
            unpackA(w0, w1, Ah[mt], Al[mt]);
        }
        #pragma unroll
        for (int nt = 0; nt < 4; ++nt) {
            int ntg = wv * 4 + nt;
            long boff = (long)((kk * 32 + ntg) * 64 + l) * 8;
            half8 Bh = *(const half8*)(gw1h + boff);
            half8 Bl = *(const half8*)(gw1l + boff);
            #pragma unroll
            for (int mt = 0; mt < 4; ++mt) {
                acc[mt][nt] = MFMA16(Ah[mt], Bh, acc[mt][nt]);
                acc[mt][nt] = MFMA16(Ah[mt], Bl, acc[mt][nt]);
                acc[mt][nt] = MFMA16(Al[mt], Bh, acc[mt][nt]);
            }
        }
    }

    const int mt2 = wv >> 1;
    f32x4 acc2[2] = {zero4, zero4};
    #pragma unroll
    for (int half = 0; half < 2; ++half) {
        __syncthreads();
        if ((wv >> 2) == half) {
            #pragma unroll
            for (int nt = 0; nt < 4; ++nt) {
                int col = wv * 64 + nt * 16 + lr;
                float bb = gb1[col];
                int ksl = (col >> 5) - half * 8;
                int kl = col & 31;
                #pragma unroll
                for (int mt = 0; mt < 4; ++mt)
                    #pragma unroll
                    for (int r = 0; r < 4; ++r) {
                        int row = mt * 16 + q * 4 + r;
                        float v = leaky(acc[mt][nt][r] + bb);
                        int sw = (((kl >> 2) ^ (row & 7)) << 2) | (kl & 3);
                        *(uint32_t*)(smem + 16384 + ksl * 8192 + row * 128 + sw * 4)
                            = packsplit(v);
                    }
            }
        }
        __syncthreads();
        #pragma unroll
        for (int ks = 0; ks < 8; ++ks) {
            int kstep = half * 8 + ks;
            int row = mt2 * 16 + lr, f = row & 7;
            const unsigned char* rb = smem + 16384 + ks * 8192 + row * 128;
            u32x4 w0 = *(const u32x4*)(rb + (((2 * q) ^ f) << 4));
            u32x4 w1 = *(const u32x4*)(rb + (((2 * q + 1) ^ f) << 4));
            half8 Ah2, Al2;
            unpackA(w0, w1, Ah2, Al2);
            #pragma unroll
            for (int nt = 0; nt < 2; ++nt) {
                int ntg = (wv & 1) * 2 + nt;
                long boff = (long)((kstep * 4 + ntg) * 64 + l) * 8;
                half8 Bh = *(const half8*)(gw2h + boff);
                half8 Bl = *(const half8*)(gw2l + boff);
                acc2[nt] = MFMA16(Ah2, Bh, acc2[nt]);
                acc2[nt] = MFMA16(Ah2, Bl, acc2[nt]);
                acc2[nt] = MFMA16(Al2, Bh, acc2[nt]);
            }
        }
    }
    #pragma unroll
    for (int nt = 0; nt < 2; ++nt) {
        int col = ((wv & 1) * 2 + nt) * 16 + lr;
        float bb = gb2[col];
        #pragma unroll
        for (int r = 0; r < 4; ++r) {
            int node = mt2 * 16 + q * 4 + r;
            emb_s[b * 4096 + node * 64 + col] = acc2[nt][r] + bb;
        }
    }
}

// ---------------- k_f3: fully fused f-MLP, 512 threads ----------------
// LDS (80 KB):
//   [0, 32768)     h0 hi-plane [row 64][512 B] (256 cols/super-chunk, granule swz)
//                  (prologue overlay: s_emb [0,16K), s_wadj [16K,32K))
//                  (epilogue overlay: part [0,4K))
//   [32768, 65536) h0 lo-plane
//   [65536, 81920) A0: aggr packed u32 [m 64][256 B], granule-XOR swizzled
// Plane granule swizzle: kg' = (kg & 16) | ((kg ^ row) & 15), kg = klocal>>3.

__global__ __launch_bounds__(512, 3) void k_f3(
    const float* __restrict__ graphs, const float* __restrict__ w,
    const float* __restrict__ emb_s, const float* __restrict__ base_f,
    const float* __restrict__ fb1, const float* __restrict__ w2P,
    const float* __restrict__ fb2,
    const _Float16* __restrict__ fw0h, const _Float16* __restrict__ fw0l,
    const _Float16* __restrict__ fw1h, const _Float16* __restrict__ fw1l,
    float* __restrict__ out)
{
    __shared__ __align__(16) unsigned char smem[81920];
    const int t = threadIdx.x, l = t & 63, wv = t >> 6;   // wv 0..7
    const int q = l >> 4, lr = l & 15;
    const int bid = blockIdx.x;
    const int m_blk = (bid & 7) * 256 + (bid >> 3);       // XCD-contiguous
    const int b = m_blk >> 3, g = m_blk & 7;

    // ---- stage emb_s[b] (16 KB) + wadj = graphs[g]*w (16 KB) ----
    {
        float* se = (float*)smem;
        float* sw = (float*)(smem + 16384);
        int idx = t * 8;
        *(float4*)(se + idx)     = *(const float4*)(emb_s + b * 4096 + idx);
        *(float4*)(se + idx + 4) = *(const float4*)(emb_s + b * 4096 + idx + 4);
        float4 g0 = *(const float4*)(graphs + g * 4096 + idx);
        float4 w0 = *(const float4*)(w + idx);
        float4 m0; m0.x = g0.x*w0.x; m0.y = g0.y*w0.y; m0.z = g0.z*w0.z; m0.w = g0.w*w0.w;
        *(float4*)(sw + idx) = m0;
        float4 g1 = *(const float4*)(graphs + g * 4096 + idx + 4);
        float4 w1 = *(const float4*)(w + idx + 4);
        float4 m1; m1.x = g1.x*w1.x; m1.y = g1.y*w1.y; m1.z = g1.z*w1.z; m1.w = g1.w*w1.w;
        *(float4*)(sw + idx + 4) = m1;
    }
    __syncthreads();

    // ---- aggr[m][k] fp32 -> packed A0 frags ----
    {
        const float* se = (const float*)smem;
        const float* sw = (const float*)(smem + 16384);
        int m = t >> 3, k0 = (t & 7) * 8;
        float acc[8] = {0.f,0.f,0.f,0.f,0.f,0.f,0.f,0.f};
        for (int j = 0; j < 64; ++j) {
            float wc = sw[j * 64 + m];
            float4 e0 = *(const float4*)(se + j * 64 + k0);
            float4 e1 = *(const float4*)(se + j * 64 + k0 + 4);
            acc[0] = fmaf(wc, e0.x, acc[0]); acc[1] = fmaf(wc, e0.y, acc[1]);
            acc[2] = fmaf(wc, e0.z, acc[2]); acc[3] = fmaf(wc, e0.w, acc[3]);
            acc[4] = fmaf(wc, e1.x, acc[4]); acc[5] = fmaf(wc, e1.y, acc[5]);
            acc[6] = fmaf(wc, e1.z, acc[6]); acc[7] = fmaf(wc, e1.w, acc[7]);
        }
        int f = m & 7;
        u32x4 p0, p1;
        #pragma unroll
        for (int e = 0; e < 4; ++e) { p0[e] = packsplit(acc[e]); p1[e] = packsplit(acc[4 + e]); }
        int g0i = k0 >> 2;   // even
        *(u32x4*)(smem + 65536 + m * 256 + ((g0i ^ f) << 4))       = p0;
        *(u32x4*)(smem + 65536 + m * 256 + (((g0i + 1) ^ f) << 4)) = p1;
    }

    f32x4 zero4 = {0.f, 0.f, 0.f, 0.f};
    f32x4 acc1[4][4];
    #pragma unroll
    for (int mt = 0; mt < 4; ++mt)
        #pragma unroll
        for (int nt = 0; nt < 4; ++nt) acc1[mt][nt] = zero4;

    for (int sc = 0; sc < 2; ++sc) {
        __syncthreads();   // sc=0: A0 ready; sc=1: all layer1 reads of h0 done

        // ---- layer0 + immediate h0 write, per (nt2, mt) ----
        #pragma unroll
        for (int nt2 = 0; nt2 < 2; ++nt2) {
            int ntg = sc * 16 + wv * 2 + nt2;
            half8 B0h[2], B0l[2];
            #pragma unroll
            for (int ks = 0; ks < 2; ++ks) {
                long boff = (long)((ks * 32 + ntg) * 64 + l) * 8;
                B0h[ks] = *(const half8*)(fw0h + boff);
                B0l[ks] = *(const half8*)(fw0l + boff);
            }
            int klocal = wv * 32 + nt2 * 16 + lr;
            int kg = klocal >> 3;
            #pragma unroll
            for (int mt = 0; mt < 4; ++mt) {
                f32x4 c0 = zero4;
                #pragma unroll
                for (int ks = 0; ks < 2; ++ks) {
                    int m = mt * 16 + lr, f = m & 7;
                    const unsigned char* rb = smem + 65536 + m * 256;
                    int gb2 = ks * 8 + 2 * q;
                    u32x4 w0 = *(const u32x4*)(rb + (((gb2)     ^ f) << 4));
                    u32x4 w1 = *(const u32x4*)(rb + (((gb2 + 1) ^ f) << 4));
                    half8 Ah, Al;
                    unpackA(w0, w1, Ah, Al);
                    c0 = MFMA16(Ah, B0h[ks], c0);
                    c0 = MFMA16(Ah, B0l[ks], c0);
                    c0 = MFMA16(Al, B0h[ks], c0);
                }
                #pragma unroll
                for (int r = 0; r < 4; ++r) {
                    int node = mt * 16 + q * 4 + r;
                    float v = leaky(c0[r] + base_f[node * 512 + sc * 256 + klocal]);
                    _Float16 hi = (_Float16)v;
                    _Float16 lo = (_Float16)(v - (float)hi);
                    int kgp = (kg & 16) | ((kg ^ node) & 15);
                    int byte = node * 512 + kgp * 16 + (lr & 7) * 2;
                    *(_Float16*)(smem + byte)         = hi;
                    *(_Float16*)(smem + 32768 + byte) = lo;
                }
            }
        }
        __syncthreads();   // h0 super-chunk ready

        // ---- layer1: 8 barrier-free K-steps over this super-chunk ----
        #pragma unroll
        for (int kkl = 0; kkl < 8; ++kkl) {
            const int kk = sc * 8 + kkl;
            half8 Ah[4], Al[4];
            #pragma unroll
            for (int mt = 0; mt < 4; ++mt) {
                int row = mt * 16 + lr;
                int kg = kkl * 4 + q;
                int kgp = (kg & 16) | ((kg ^ row) & 15);
                int ab = row * 512 + kgp * 16;
                Ah[mt] = *(const half8*)(smem + ab);
                Al[mt] = *(const half8*)(smem + 32768 + ab);
            }
            #pragma unroll
            for (int nt = 0; nt < 4; ++nt) {
                int ntg = wv * 4 + nt;
                long boff = (long)((kk * 32 + ntg) * 64 + l) * 8;
                half8 Bh = *(const half8*)(fw1h + boff);
                half8 Bl = *(const half8*)(fw1l + boff);
                __builtin_amdgcn_s_setprio(1);
                #pragma unroll
                for (int mt = 0; mt < 4; ++mt) {
                    acc1[mt][nt] = MFMA16(Ah[mt], Bh, acc1[mt][nt]);
                    acc1[mt][nt] = MFMA16(Ah[mt], Bl, acc1[mt][nt]);
                    acc1[mt][nt] = MFMA16(Al[mt], Bh, acc1[mt][nt]);
                }
                __builtin_amdgcn_s_setprio(0);
            }
        }
    }

    __syncthreads();   // layer1 reads done; safe to overlay part into h0hi
    // ---- h1 bias/leaky + fused layer2 partial dots ----
    float* part = (float*)smem;   // [wv 8][node 64][d 2] = 4 KB
    #pragma unroll
    for (int mt = 0; mt < 4; ++mt) {
        float s0[4] = {0.f, 0.f, 0.f, 0.f}, s1[4] = {0.f, 0.f, 0.f, 0.f};
        #pragma unroll
        for (int nt = 0; nt < 4; ++nt) {
            int col = wv * 64 + nt * 16 + lr;
            float bb = fb1[col];
            #pragma unroll
            for (int r = 0; r < 4; ++r) {
                int node = mt * 16 + q * 4 + r;
                float h1 = leaky(acc1[mt][nt][r] + bb);
                float2 w2 = *(const float2*)(w2P + (((size_t)node * 512 + col) << 1));
                s0[r] = fmaf(h1, w2.x, s0[r]);
                s1[r] = fmaf(h1, w2.y, s1[r]);
            }
        }
        #pragma unroll
        for (int r = 0; r < 4; ++r) {
            s0[r] += __shfl_xor(s0[r], 1, 64); s0[r] += __shfl_xor(s0[r], 2, 64);
            s0[r] += __shfl_xor(s0[r], 4, 64); s0[r] += __shfl_xor(s0[r], 8, 64);
            s1[r] += __shfl_xor(s1[r], 1, 64); s1[r] += __shfl_xor(s1[r], 2, 64);
            s1[r] += __shfl_xor(s1[r], 4, 64); s1[r] += __shfl_xor(s1[r], 8, 64);
            if (lr == 0) {
                int node = mt * 16 + q * 4 + r;
                part[wv * 128 + node * 2 + 0] = s0[r];
                part[wv * 128 + node * 2 + 1] = s1[r];
            }
        }
    }
    __syncthreads();
    if (t < 128) {
        float s = 0.f;
        #pragma unroll
        for (int v8 = 0; v8 < 8; ++v8) s += part[v8 * 128 + t];
        out[m_blk * 128 + t] = s + fb2[t];
    }
}

// ---------------- launch ----------------

extern "C" void kernel_launch(void* const* d_in, const int* in_sizes, int n_in,
                              void* d_out, int out_size, void* d_ws, size_t ws_size,
                              hipStream_t stream)
{
    const float* samples    = (const float*)d_in[0];
    const float* graphs     = (const float*)d_in[1];
    const float* embeddings = (const float*)d_in[3];
    const float* w          = (const float*)d_in[4];
    const float* g_w0 = (const float*)d_in[5];
    const float* g_b0 = (const float*)d_in[6];
    const float* g_w1 = (const float*)d_in[7];
    const float* g_b1 = (const float*)d_in[8];
    const float* g_w2 = (const float*)d_in[9];
    const float* g_b2 = (const float*)d_in[10];
    const float* f_w0 = (const float*)d_in[11];
    const float* f_b0 = (const float*)d_in[12];
    const float* f_w1 = (const float*)d_in[13];
    const float* f_b1 = (const float*)d_in[14];
    const float* f_w2 = (const float*)d_in[15];
    const float* f_b2 = (const float*)d_in[16];
    float* out = (float*)d_out;

    float* ws     = (float*)d_ws;
    float* base_g = ws;                    // 32768 f
    float* base_f = ws + 32768;            // 32768 f
    float* w2P    = ws + 65536;            // 65536 f
    float* emb_s  = ws + 131072;           // 1048576 f
    _Float16* f16b = (_Float16*)(ws + 1179648);
    _Float16* fw1h = f16b;                 // 262144 h
    _Float16* fw1l = f16b + 262144;
    _Float16* fw0h = f16b + 524288;        // 32768 h
    _Float16* fw0l = f16b + 557056;
    _Float16* gw1h = f16b + 589824;        // 262144 h
    _Float16* gw1l = f16b + 851968;
    _Float16* gw2h = f16b + 1114112;       // 32768 h
    _Float16* gw2l = f16b + 1146880;       // end ~7.1 MB of ws

    hipLaunchKernelGGL(k_base, dim3(256), dim3(256), 0, stream,
                       embeddings, g_w0, g_b0, f_w0, f_b0, base_g, base_f);
    hipLaunchKernelGGL(k_w2p, dim3(256), dim3(256), 0, stream, f_w2, w2P);
    hipLaunchKernelGGL(k_splitw, dim3(288), dim3(256), 0, stream,
                       f_w0, f_w1, g_w1, g_w2,
                       fw0h, fw0l, fw1h, fw1l, gw1h, gw1l, gw2h, gw2l);
    hipLaunchKernelGGL(k_gmlp, dim3(256), dim3(512), 0, stream,
                       samples, g_w0, base_g, g_b1, g_b2,
                       gw1h, gw1l, gw2h, gw2l, emb_s);
    hipLaunchKernelGGL(k_f3, dim3(2048), dim3(512), 0, stream,
                       graphs, w, emb_s, base_f, f_b1, w2P, f_b2,
                       fw0h, fw0l, fw1h, fw1l, out);
}

// Round 16
// 338.227 us; speedup vs baseline: 1.6413x; 1.6413x over previous
//
#include <hip/hip_runtime.h>
#include <stdint.h>

// N=64, D=128, EMB=64, OUTG=64, A=512, B=256, G=8
// group_mask[i,j] = (j//2 == i).
//
// k_f6 (ROUND 16, on the round-11 keeper config (512,2)):
//  - aggr moved to MFMA: wadjT/emb_s split-f16 frags built in LDS (transposed,
//    conflict-free), 12 MFMA/wave replaces the 1024-FMA fp32 VALU loop.
//  - emb contribution folded into layer0 (K=128; ks 2,3 read precomputed embA
//    frags); base_f replaced by fb0 broadcast (kills 64 scalar loads/thread).
// Rounds 12-15 all regressed and are reverted: reg budget = 512/min_waves TOTAL
// (arch+acc unified); (512,2)=256 is the only spill-free point for this tile.
//   frags -> barrier -> aggr MFMA -> A0 frags ->
//   2 super-chunks of 256 h0-cols:
//     barrier -> layer0 MFMA (K=128) + fb0/leaky -> h0 two-plane f16 hi/lo LDS
//     (granule-XOR swz) -> barrier -> 8 barrier-free layer1 K-steps
//   epilogue: +fb1/leaky -> fused layer2 partial dots -> LDS reduce -> out.
// fp16-split x3 MFMA: a = a_hi+a_lo; a*b ~= AhBh + AhBl + AlBh (fp32 acc).

typedef _Float16 half8 __attribute__((ext_vector_type(8)));
typedef float    f32x4 __attribute__((ext_vector_type(4)));
typedef uint32_t u32x4 __attribute__((ext_vector_type(4)));

#define MFMA16(a, b, c) __builtin_amdgcn_mfma_f32_16x16x32_f16(a, b, c, 0, 0, 0)

__device__ __forceinline__ float leaky(float v) { return v >= 0.f ? v : 0.01f * v; }

__device__ __forceinline__ uint32_t packsplit(float v) {
    _Float16 hi = (_Float16)v;
    _Float16 lo = (_Float16)(v - (float)hi);
    union { _Float16 f; unsigned short u; } a, c;
    a.f = hi; c.f = lo;
    return (uint32_t)a.u | ((uint32_t)c.u << 16);
}

__device__ __forceinline__ void unpackA(u32x4 w0, u32x4 w1, half8& Ah, half8& Al) {
    union { u32x4 u; half8 h; } ah, al;
    ah.u[0] = (w0[0] & 0xffffu) | (w0[1] << 16);
    ah.u[1] = (w0[2] & 0xffffu) | (w0[3] << 16);
    ah.u[2] = (w1[0] & 0xffffu) | (w1[1] << 16);
    ah.u[3] = (w1[2] & 0xffffu) | (w1[3] << 16);
    al.u[0] = (w0[0] >> 16) | (w0[1] & 0xffff0000u);
    al.u[1] = (w0[2] >> 16) | (w0[3] & 0xffff0000u);
    al.u[2] = (w1[0] >> 16) | (w1[1] & 0xffff0000u);
    al.u[3] = (w1[2] >> 16) | (w1[3] & 0xffff0000u);
    Ah = ah.h; Al = al.h;
}

// ---------------- prep kernels ----------------

__global__ void k_base(const float* __restrict__ emb,
                       const float* __restrict__ gw0, const float* __restrict__ gb0,
                       const float* __restrict__ fw0, const float* __restrict__ fb0,
                       float* __restrict__ base_g, float* __restrict__ base_f)
{
    int blk = blockIdx.x;            // 256 blocks
    int n     = blk >> 2;
    int half  = (blk >> 1) & 1;
    int which = blk & 1;
    int c = half * 256 + threadIdx.x;
    const float* W    = which ? fw0 : gw0;
    const float* bias = which ? fb0 : gb0;
    float* dst        = which ? base_f : base_g;
    int off           = which ? 64 : 128;
    const float* e = emb + n * 64;
    float acc = bias[c];
    #pragma unroll 8
    for (int k = 0; k < 64; ++k)
        acc = fmaf(e[k], W[(off + k) * 512 + c], acc);
    dst[n * 512 + c] = acc;
}

// w2P[node][a][d] = fw2[a][2*node+d]
__global__ void k_w2p(const float* __restrict__ fw2, float* __restrict__ w2P)
{
    int tid = blockIdx.x * 256 + threadIdx.x;   // grid 256 -> 65536
    int c = tid >> 9, a = tid & 511;            // c = 2*node+d
    int node = c >> 1, d = c & 1;
    w2P[(node * 512 + a) * 2 + d] = fw2[a * 128 + c];
}

// Fragment-linear f16 hi/lo splits (operand layout for mfma 16x16x32,
// lane l, reg j -> W[kstep*32+(l>>4)*8+j][tile*16+(l&15)]):
//  blocks [0,128):   fw1 (512x512), 16 ksteps x 32 ntg
//  blocks [128,160): fw0 FULL 128 rows, 4 ksteps x 32 ntg
//  blocks [160,288): gw1 (512x512)
//  blocks [288,304): gw2 (512x64), 16 ksteps x 4 ntg
//  blocks [304,306): embA: A-frags of embeddings (64x64), frag f = mtA*2+ks2
__global__ void k_splitw(const float* __restrict__ fw0, const float* __restrict__ fw1,
                         const float* __restrict__ gw1, const float* __restrict__ gw2,
                         const float* __restrict__ emb,
                         _Float16* __restrict__ fw0h, _Float16* __restrict__ fw0l,
                         _Float16* __restrict__ fw1h, _Float16* __restrict__ fw1l,
                         _Float16* __restrict__ gw1h, _Float16* __restrict__ gw1l,
                         _Float16* __restrict__ gw2h, _Float16* __restrict__ gw2l,
                         _Float16* __restrict__ embAh, _Float16* __restrict__ embAl)
{
    int tid = blockIdx.x * 256 + threadIdx.x;
    if (blockIdx.x < 128) {                       // fw1
        int l = tid & 63, grp = tid >> 6;
        int kstep = grp >> 5, ntg = grp & 31;
        #pragma unroll
        for (int j = 0; j < 8; ++j) {
            int k = kstep * 32 + (l >> 4) * 8 + j;
            int n = ntg * 16 + (l & 15);
            float v = fw1[k * 512 + n];
            _Float16 h = (_Float16)v;
            fw1h[tid * 8 + j] = h;
            fw1l[tid * 8 + j] = (_Float16)(v - (float)h);
        }
    } else if (blockIdx.x < 160) {                // fw0 full 128 rows
        int t2 = tid - 32768;                     // 0..8191
        int l = t2 & 63, grp = t2 >> 6;           // grp 0..127
        int kstep = grp >> 5, ntg = grp & 31;
        #pragma unroll
        for (int j = 0; j < 8; ++j) {
            int k = kstep * 32 + (l >> 4) * 8 + j;
            int n = ntg * 16 + (l & 15);
            float v = fw0[k * 512 + n];
            _Float16 h = (_Float16)v;
            fw0h[t2 * 8 + j] = h;
            fw0l[t2 * 8 + j] = (_Float16)(v - (float)h);
        }
    } else if (blockIdx.x < 288) {                // gw1
        int t4 = tid - 40960;
        int l = t4 & 63, grp = t4 >> 6;
        int kstep = grp >> 5, ntg = grp & 31;
        #pragma unroll
        for (int j = 0; j < 8; ++j) {
            int k = kstep * 32 + (l >> 4) * 8 + j;
            int n = ntg * 16 + (l & 15);
            float v = gw1[k * 512 + n];
            _Float16 h = (_Float16)v;
            gw1h[t4 * 8 + j] = h;
            gw1l[t4 * 8 + j] = (_Float16)(v - (float)h);
        }
    } else if (blockIdx.x < 304) {                // gw2
        int t3 = tid - 73728;                     // 0..4095
        int l = t3 & 63, grp = t3 >> 6;           // grp 0..63
        int kstep = grp >> 2, ntg = grp & 3;
        #pragma unroll
        for (int j = 0; j < 8; ++j) {
            int k = kstep * 32 + (l >> 4) * 8 + j;
            int n = ntg * 16 + (l & 15);
            float v = gw2[k * 64 + n];
            _Float16 h = (_Float16)v;
            gw2h[t3 * 8 + j] = h;
            gw2l[t3 * 8 + j] = (_Float16)(v - (float)h);
        }
    } else {                                      // embA A-frags
        int t5 = tid - 77824;                     // 0..511
        int l = t5 & 63, f = t5 >> 6;             // f = mtA*2 + ks2
        int mtA = f >> 1, ks2 = f & 1;
        #pragma unroll
        for (int j = 0; j < 8; ++j) {
            int m = mtA * 16 + (l & 15);
            int k = ks2 * 32 + (l >> 4) * 8 + j;
            float v = emb[m * 64 + k];
            _Float16 h = (_Float16)v;
            embAh[t5 * 8 + j] = h;
            embAl[t5 * 8 + j] = (_Float16)(v - (float)h);
        }
    }
}

// ---------------- k_gmlp: g-MLP on MFMA (unchanged) ----------------

__global__ __launch_bounds__(512, 2) void k_gmlp(
    const float* __restrict__ samples, const float* __restrict__ gw0,
    const float* __restrict__ base_g, const float* __restrict__ gb1,
    const float* __restrict__ gb2,
    const _Float16* __restrict__ gw1h, const _Float16* __restrict__ gw1l,
    const _Float16* __restrict__ gw2h, const _Float16* __restrict__ gw2l,
    float* __restrict__ emb_s)
{
    __shared__ __align__(16) unsigned char smem[81920];
    const int t = threadIdx.x, l = t & 63, wv = t >> 6;
    const int q = l >> 4, lr = l & 15;
    const int b = blockIdx.x;

    f32x4 zero4 = {0.f, 0.f, 0.f, 0.f};
    f32x4 acc[4][4];
    #pragma unroll
    for (int mt = 0; mt < 4; ++mt)
        #pragma unroll
        for (int nt = 0; nt < 4; ++nt) acc[mt][nt] = zero4;

    auto stage = [&](int kk, int bq) {
        #pragma unroll
        for (int it = 0; it < 4; ++it) {
            int n = it * 16 + (t >> 5);
            int c = kk * 32 + (t & 31);
            float s0 = samples[b * 128 + 2 * n];
            float s1 = samples[b * 128 + 2 * n + 1];
            float v = fmaf(s0, gw0[(2 * n) * 512 + c],
                      fmaf(s1, gw0[(2 * n + 1) * 512 + c], base_g[n * 512 + c]));
            v = leaky(v);
            int kl = t & 31;
            int sw = (((kl >> 2) ^ (n & 7)) << 2) | (kl & 3);
            *(uint32_t*)(smem + bq * 8192 + n * 128 + sw * 4) = packsplit(v);
        }
    };

    stage(0, 0);
    for (int kk = 0; kk < 16; ++kk) {
        const int pb = kk & 1;
        __syncthreads();
        if (kk < 15) stage(kk + 1, pb ^ 1);

        half8 Ah[4], Al[4];
        #pragma unroll
        for (int mt = 0; mt < 4; ++mt) {
            int row = mt * 16 + lr, f = row & 7;
            const unsigned char* rb = smem + pb * 8192 + row * 128;
            u32x4 w0 = *(const u32x4*)(rb + (((2 * q) ^ f) << 4));
            u32x4 w1 = *(const u32x4*)(rb + (((2 * q + 1) ^ f) << 4));
            unpackA(w0, w1, Ah[mt], Al[mt]);
        }
        #pragma unroll
        for (int nt = 0; nt < 4; ++nt) {
            int ntg = wv * 4 + nt;
            long boff = (long)((kk * 32 + ntg) * 64 + l) * 8;
            half8 Bh = *(const half8*)(gw1h + boff);
            half8 Bl = *(const half8*)(gw1l + boff);
            #pragma unroll
            for (int mt = 0; mt < 4; ++mt) {
                acc[mt][nt] = MFMA16(Ah[mt], Bh, acc[mt][nt]);
                acc[mt][nt] = MFMA16(Ah[mt], Bl, acc[mt][nt]);
                acc[mt][nt] = MFMA16(Al[mt], Bh, acc[mt][nt]);
            }
        }
    }

    const int mt2 = wv >> 1;
    f32x4 acc2[2] = {zero4, zero4};
    #pragma unroll
    for (int half = 0; half < 2; ++half) {
        __syncthreads();
        if ((wv >> 2) == half) {
            #pragma unroll
            for (int nt = 0; nt < 4; ++nt) {
                int col = wv * 64 + nt * 16 + lr;
                float bb = gb1[col];
                int ksl = (col >> 5) - half * 8;
                int kl = col & 31;
                #pragma unroll
                for (int mt = 0; mt < 4; ++mt)
                    #pragma unroll
                    for (int r = 0; r < 4; ++r) {
                        int row = mt * 16 + q * 4 + r;
                        float v = leaky(acc[mt][nt][r] + bb);
                        int sw = (((kl >> 2) ^ (row & 7)) << 2) | (kl & 3);
                        *(uint32_t*)(smem + 16384 + ksl * 8192 + row * 128 + sw * 4)
                            = packsplit(v);
                    }
            }
        }
        __syncthreads();
        #pragma unroll
        for (int ks = 0; ks < 8; ++ks) {
            int kstep = half * 8 + ks;
            int row = mt2 * 16 + lr, f = row & 7;
            const unsigned char* rb = smem + 16384 + ks * 8192 + row * 128;
            u32x4 w0 = *(const u32x4*)(rb + (((2 * q) ^ f) << 4));
            u32x4 w1 = *(const u32x4*)(rb + (((2 * q + 1) ^ f) << 4));
            half8 Ah2, Al2;
            unpackA(w0, w1, Ah2, Al2);
            #pragma unroll
            for (int nt = 0; nt < 2; ++nt) {
                int ntg = (wv & 1) * 2 + nt;
                long boff = (long)((kstep * 4 + ntg) * 64 + l) * 8;
                half8 Bh = *(const half8*)(gw2h + boff);
                half8 Bl = *(const half8*)(gw2l + boff);
                acc2[nt] = MFMA16(Ah2, Bh, acc2[nt]);
                acc2[nt] = MFMA16(Ah2, Bl, acc2[nt]);
                acc2[nt] = MFMA16(Al2, Bh, acc2[nt]);
            }
        }
    }
    #pragma unroll
    for (int nt = 0; nt < 2; ++nt) {
        int col = ((wv & 1) * 2 + nt) * 16 + lr;
        float bb = gb2[col];
        #pragma unroll
        for (int r = 0; r < 4; ++r) {
            int node = mt2 * 16 + q * 4 + r;
            emb_s[b * 4096 + node * 64 + col] = acc2[nt][r] + bb;
        }
    }
}

// ---------------- k_f6: fully fused f-MLP, aggr+emb on MFMA ----------------
// LDS (80 KB):
//   [0, 16384)     phase1: wadjT frags (u32 at frag*2048 + j*256 + l*4)
//                  then h0 hi-plane [row 64][512 B] (granule swz); part overlay
//   [16384, 32768) phase1: emb_s frags; then part of h0 hi/lo planes
//   [0, 32768)     h0 hi-plane;  [32768, 65536) h0 lo-plane
//   [65536, 81920) A0: aggr packed u32 [m 64][256 B], granule-XOR swizzled
// Plane granule swizzle: kg' = (kg & 16) | ((kg ^ row) & 15), kg = klocal>>3.

__global__ __launch_bounds__(512, 2) void k_f6(
    const float* __restrict__ graphs, const float* __restrict__ w,
    const float* __restrict__ emb_s,
    const float* __restrict__ fb0, const float* __restrict__ fb1,
    const float* __restrict__ w2P, const float* __restrict__ fb2,
    const _Float16* __restrict__ fw0h, const _Float16* __restrict__ fw0l,
    const _Float16* __restrict__ fw1h, const _Float16* __restrict__ fw1l,
    const _Float16* __restrict__ embAh, const _Float16* __restrict__ embAl,
    float* __restrict__ out)
{
    __shared__ __align__(16) unsigned char smem[81920];
    const int t = threadIdx.x, l = t & 63, wv = t >> 6;   // wv 0..7
    const int q = l >> 4, lr = l & 15;
    const int bid = blockIdx.x;
    const int m_blk = (bid & 7) * 256 + (bid >> 3);       // XCD-contiguous
    const int b = m_blk >> 3, g = m_blk & 7;

    // ---- Phase 1: split-f16 frags of wadjT and emb_s, direct from global ----
    {
        int mtW = wv >> 1, ksW = wv & 1;
        int jbase = ksW * 32 + (l >> 4) * 8;
        int col16 = mtW * 16 + (l & 15);          // m-col (wadjT) == k-col (emb)
        #pragma unroll
        for (int j = 0; j < 8; ++j) {
            int jrow = jbase + j;
            float va = graphs[g * 4096 + jrow * 64 + col16] * w[jrow * 64 + col16];
            float vb = emb_s[b * 4096 + jrow * 64 + col16];
            *(uint32_t*)(smem + wv * 2048 + j * 256 + l * 4)         = packsplit(va);
            *(uint32_t*)(smem + 16384 + wv * 2048 + j * 256 + l * 4) = packsplit(vb);
        }
    }
    __syncthreads();

    // ---- Phase 2: aggr = wadjT @ emb_s via MFMA -> A0 frags at 65536 ----
    {
        #pragma unroll
        for (int cc2 = 0; cc2 < 2; ++cc2) {
            int combo = wv * 2 + cc2;
            int mtA = combo >> 2, ntA = combo & 3;
            f32x4 c = {0.f, 0.f, 0.f, 0.f};
            #pragma unroll
            for (int ks = 0; ks < 2; ++ks) {
                const unsigned char* ab = smem + (mtA * 2 + ks) * 2048 + l * 4;
                const unsigned char* bb = smem + 16384 + (ntA * 2 + ks) * 2048 + l * 4;
                u32x4 a0, a1, b0, b1;
                #pragma unroll
                for (int e = 0; e < 4; ++e) {
                    a0[e] = *(const uint32_t*)(ab + e * 256);
                    a1[e] = *(const uint32_t*)(ab + (4 + e) * 256);
                    b0[e] = *(const uint32_t*)(bb + e * 256);
                    b1[e] = *(const uint32_t*)(bb + (4 + e) * 256);
                }
                half8 Ah, Al, Bh, Bl;
                unpackA(a0, a1, Ah, Al);
                unpackA(b0, b1, Bh, Bl);
                c = MFMA16(Ah, Bh, c);
                c = MFMA16(Ah, Bl, c);
                c = MFMA16(Al, Bh, c);
            }
            #pragma unroll
            for (int r = 0; r < 4; ++r) {
                int node = mtA * 16 + (l >> 4) * 4 + r;
                int kf = ntA * 16 + (l & 15);
                *(uint32_t*)(smem + 65536 + node * 256 +
                             (((kf >> 2) ^ (node & 7)) << 4) + (kf & 3) * 4)
                    = packsplit(c[r]);
            }
        }
    }

    f32x4 zero4 = {0.f, 0.f, 0.f, 0.f};
    f32x4 acc1[4][4];
    #pragma unroll
    for (int mt = 0; mt < 4; ++mt)
        #pragma unroll
        for (int nt = 0; nt < 4; ++nt) acc1[mt][nt] = zero4;

    for (int sc = 0; sc < 2; ++sc) {
        __syncthreads();   // sc=0: A0 + frag reads done; sc=1: layer1 h0 reads done

        // ---- layer0 K=128 (ks0,1: A0 LDS; ks2,3: embA global) + h0 write ----
        #pragma unroll
        for (int nt2 = 0; nt2 < 2; ++nt2) {
            int ntg = sc * 16 + wv * 2 + nt2;
            half8 B0h[4], B0l[4];
            #pragma unroll
            for (int ks = 0; ks < 4; ++ks) {
                long boff = (long)((ks * 32 + ntg) * 64 + l) * 8;
                B0h[ks] = *(const half8*)(fw0h + boff);
                B0l[ks] = *(const half8*)(fw0l + boff);
            }
            int klocal = wv * 32 + nt2 * 16 + lr;
            int kg = klocal >> 3;
            float b0v = fb0[sc * 256 + klocal];
            #pragma unroll
            for (int mt = 0; mt < 4; ++mt) {
                f32x4 c0 = zero4;
                #pragma unroll
                for (int ks = 0; ks < 2; ++ks) {
                    int m = mt * 16 + lr, f = m & 7;
                    const unsigned char* rb = smem + 65536 + m * 256;
                    int gb2 = ks * 8 + 2 * q;
                    u32x4 w0 = *(const u32x4*)(rb + (((gb2)     ^ f) << 4));
                    u32x4 w1 = *(const u32x4*)(rb + (((gb2 + 1) ^ f) << 4));
                    half8 Ah, Al;
                    unpackA(w0, w1, Ah, Al);
                    c0 = MFMA16(Ah, B0h[ks], c0);
                    c0 = MFMA16(Ah, B0l[ks], c0);
                    c0 = MFMA16(Al, B0h[ks], c0);
                }
                #pragma unroll
                for (int ks = 2; ks < 4; ++ks) {
                    long aoff = (long)((mt * 2 + (ks - 2)) * 64 + l) * 8;
                    half8 Ah = *(const half8*)(embAh + aoff);
                    half8 Al = *(const half8*)(embAl + aoff);
                    c0 = MFMA16(Ah, B0h[ks], c0);
                    c0 = MFMA16(Ah, B0l[ks], c0);
                    c0 = MFMA16(Al, B0h[ks], c0);
                }
                #pragma unroll
                for (int r = 0; r < 4; ++r) {
                    int node = mt * 16 + q * 4 + r;
                    float v = leaky(c0[r] + b0v);
                    _Float16 hi = (_Float16)v;
                    _Float16 lo = (_Float16)(v - (float)hi);
                    int kgp = (kg & 16) | ((kg ^ node) & 15);
                    int byte = node * 512 + kgp * 16 + (lr & 7) * 2;
                    *(_Float16*)(smem + byte)         = hi;
                    *(_Float16*)(smem + 32768 + byte) = lo;
                }
            }
        }
        __syncthreads();   // h0 super-chunk ready

        // ---- layer1: 8 barrier-free K-steps over this super-chunk ----
        #pragma unroll
        for (int kkl = 0; kkl < 8; ++kkl) {
            const int kk = sc * 8 + kkl;
            half8 Ah[4], Al[4];
            #pragma unroll
            for (int mt = 0; mt < 4; ++mt) {
                int row = mt * 16 + lr;
                int kg = kkl * 4 + q;
                int kgp = (kg & 16) | ((kg ^ row) & 15);
                int ab = row * 512 + kgp * 16;
                Ah[mt] = *(const half8*)(smem + ab);
                Al[mt] = *(const half8*)(smem + 32768 + ab);
            }
            #pragma unroll
            for (int nt = 0; nt < 4; ++nt) {
                int ntg = wv * 4 + nt;
                long boff = (long)((kk * 32 + ntg) * 64 + l) * 8;
                half8 Bh = *(const half8*)(fw1h + boff);
                half8 Bl = *(const half8*)(fw1l + boff);
                __builtin_amdgcn_s_setprio(1);
                #pragma unroll
                for (int mt = 0; mt < 4; ++mt) {
                    acc1[mt][nt] = MFMA16(Ah[mt], Bh, acc1[mt][nt]);
                    acc1[mt][nt] = MFMA16(Ah[mt], Bl, acc1[mt][nt]);
                    acc1[mt][nt] = MFMA16(Al[mt], Bh, acc1[mt][nt]);
                }
                __builtin_amdgcn_s_setprio(0);
            }
        }
    }

    __syncthreads();   // layer1 reads done; safe to overlay part into h0hi
    // ---- h1 bias/leaky + fused layer2 partial dots ----
    float* part = (float*)smem;   // [wv 8][node 64][d 2] = 4 KB
    #pragma unroll
    for (int mt = 0; mt < 4; ++mt) {
        float s0[4] = {0.f, 0.f, 0.f, 0.f}, s1[4] = {0.f, 0.f, 0.f, 0.f};
        #pragma unroll
        for (int nt = 0; nt < 4; ++nt) {
            int col = wv * 64 + nt * 16 + lr;
            float bb = fb1[col];
            #pragma unroll
            for (int r = 0; r < 4; ++r) {
                int node = mt * 16 + q * 4 + r;
                float h1 = leaky(acc1[mt][nt][r] + bb);
                float2 w2 = *(const float2*)(w2P + (((size_t)node * 512 + col) << 1));
                s0[r] = fmaf(h1, w2.x, s0[r]);
                s1[r] = fmaf(h1, w2.y, s1[r]);
            }
        }
        #pragma unroll
        for (int r = 0; r < 4; ++r) {
            s0[r] += __shfl_xor(s0[r], 1, 64); s0[r] += __shfl_xor(s0[r], 2, 64);
            s0[r] += __shfl_xor(s0[r], 4, 64); s0[r] += __shfl_xor(s0[r], 8, 64);
            s1[r] += __shfl_xor(s1[r], 1, 64); s1[r] += __shfl_xor(s1[r], 2, 64);
            s1[r] += __shfl_xor(s1[r], 4, 64); s1[r] += __shfl_xor(s1[r], 8, 64);
            if (lr == 0) {
                int node = mt * 16 + q * 4 + r;
                part[wv * 128 + node * 2 + 0] = s0[r];
                part[wv * 128 + node * 2 + 1] = s1[r];
            }
        }
    }
    __syncthreads();
    if (t < 128) {
        float s = 0.f;
        #pragma unroll
        for (int v8 = 0; v8 < 8; ++v8) s += part[v8 * 128 + t];
        out[m_blk * 128 + t] = s + fb2[t];
    }
}

// ---------------- launch ----------------

extern "C" void kernel_launch(void* const* d_in, const int* in_sizes, int n_in,
                              void* d_out, int out_size, void* d_ws, size_t ws_size,
                              hipStream_t stream)
{
    const float* samples    = (const float*)d_in[0];
    const float* graphs     = (const float*)d_in[1];
    const float* embeddings = (const float*)d_in[3];
    const float* w          = (const float*)d_in[4];
    const float* g_w0 = (const float*)d_in[5];
    const float* g_b0 = (const float*)d_in[6];
    const float* g_w1 = (const float*)d_in[7];
    const float* g_b1 = (const float*)d_in[8];
    const float* g_w2 = (const float*)d_in[9];
    const float* g_b2 = (const float*)d_in[10];
    const float* f_w0 = (const float*)d_in[11];
    const float* f_b0 = (const float*)d_in[12];
    const float* f_w1 = (const float*)d_in[13];
    const float* f_b1 = (const float*)d_in[14];
    const float* f_w2 = (const float*)d_in[15];
    const float* f_b2 = (const float*)d_in[16];
    float* out = (float*)d_out;

    float* ws     = (float*)d_ws;
    float* base_g = ws;                    // 32768 f
    float* base_f = ws + 32768;            // 32768 f (unused by k_f6; k_base keeps writing it)
    float* w2P    = ws + 65536;            // 65536 f
    float* emb_s  = ws + 131072;           // 1048576 f
    _Float16* f16b = (_Float16*)(ws + 1179648);
    _Float16* fw1h  = f16b;                // 262144 h
    _Float16* fw1l  = f16b + 262144;
    _Float16* fw0h  = f16b + 524288;       // 65536 h (full 128 rows)
    _Float16* fw0l  = f16b + 589824;
    _Float16* gw1h  = f16b + 655360;       // 262144 h
    _Float16* gw1l  = f16b + 917504;
    _Float16* gw2h  = f16b + 1179648;      // 32768 h
    _Float16* gw2l  = f16b + 1212416;
    _Float16* embAh = f16b + 1245184;      // 4096 h
    _Float16* embAl = f16b + 1249280;      // end 1253376 h (~7.2 MB of ws)

    hipLaunchKernelGGL(k_base, dim3(256), dim3(256), 0, stream,
                       embeddings, g_w0, g_b0, f_w0, f_b0, base_g, base_f);
    hipLaunchKernelGGL(k_w2p, dim3(256), dim3(256), 0, stream, f_w2, w2P);
    hipLaunchKernelGGL(k_splitw, dim3(306), dim3(256), 0, stream,
                       f_w0, f_w1, g_w1, g_w2, embeddings,
                       fw0h, fw0l, fw1h, fw1l, gw1h, gw1l, gw2h, gw2l,
                       embAh, embAl);
    hipLaunchKernelGGL(k_gmlp, dim3(256), dim3(512), 0, stream,
                       samples, g_w0, base_g, g_b1, g_b2,
                       gw1h, gw1l, gw2h, gw2l, emb_s);
    hipLaunchKernelGGL(k_f6, dim3(2048), dim3(512), 0, stream,
                       graphs, w, emb_s, f_b0, f_b1, w2P, f_b2,
                       fw0h, fw0l, fw1h, fw1l, embAh, embAl, out);
}

// Round 17
// 287.355 us; speedup vs baseline: 1.9319x; 1.1770x over previous
//
#include <hip/hip_runtime.h>
#include <stdint.h>

// N=64, D=128, EMB=64, OUTG=64, A=512, B=256, G=8
// group_mask[i,j] = (j//2 == i).
//
// k_f7 (ROUND 17, on k_f6): activations rounded to f16 (single plane), weights
// kept split -> x2 MFMA (A_f16*Bh + A_f16*Bl) instead of x3. MFMA/wave 972->652,
// LDS 80->40 KB, h0 epilogue halved. Error budget: activation rounding adds
// ~2.4e-4/layer, RSS ~5e-4 < 1.38e-3 threshold (canary: absmax).
//   phase1: wadjT/emb_s split frags -> phase2: aggr MFMA (x3) -> A0 f16 plane
//   2 super-chunks of 256 h0-cols:
//     barrier -> layer0 MFMA x2 (K=128: A0 + embA f16 planes) + fb0/leaky ->
//     h0 f16 plane (granule swz) -> barrier -> 8 layer1 K-steps (x2, acc[4][4])
//   epilogue: +fb1/leaky -> fused layer2 partial dots -> LDS reduce -> out.

typedef _Float16 half8 __attribute__((ext_vector_type(8)));
typedef float    f32x4 __attribute__((ext_vector_type(4)));
typedef uint32_t u32x4 __attribute__((ext_vector_type(4)));

#define MFMA16(a, b, c) __builtin_amdgcn_mfma_f32_16x16x32_f16(a, b, c, 0, 0, 0)

__device__ __forceinline__ float leaky(float v) { return v >= 0.f ? v : 0.01f * v; }

__device__ __forceinline__ uint32_t packsplit(float v) {
    _Float16 hi = (_Float16)v;
    _Float16 lo = (_Float16)(v - (float)hi);
    union { _Float16 f; unsigned short u; } a, c;
    a.f = hi; c.f = lo;
    return (uint32_t)a.u | ((uint32_t)c.u << 16);
}

__device__ __forceinline__ void unpackA(u32x4 w0, u32x4 w1, half8& Ah, half8& Al) {
    union { u32x4 u; half8 h; } ah, al;
    ah.u[0] = (w0[0] & 0xffffu) | (w0[1] << 16);
    ah.u[1] = (w0[2] & 0xffffu) | (w0[3] << 16);
    ah.u[2] = (w1[0] & 0xffffu) | (w1[1] << 16);
    ah.u[3] = (w1[2] & 0xffffu) | (w1[3] << 16);
    al.u[0] = (w0[0] >> 16) | (w0[1] & 0xffff0000u);
    al.u[1] = (w0[2] >> 16) | (w0[3] & 0xffff0000u);
    al.u[2] = (w1[0] >> 16) | (w1[1] & 0xffff0000u);
    al.u[3] = (w1[2] >> 16) | (w1[3] & 0xffff0000u);
    Ah = ah.h; Al = al.h;
}

// ---------------- prep kernels ----------------

__global__ void k_base(const float* __restrict__ emb,
                       const float* __restrict__ gw0, const float* __restrict__ gb0,
                       const float* __restrict__ fw0, const float* __restrict__ fb0,
                       float* __restrict__ base_g, float* __restrict__ base_f)
{
    int blk = blockIdx.x;            // 256 blocks
    int n     = blk >> 2;
    int half  = (blk >> 1) & 1;
    int which = blk & 1;
    int c = half * 256 + threadIdx.x;
    const float* W    = which ? fw0 : gw0;
    const float* bias = which ? fb0 : gb0;
    float* dst        = which ? base_f : base_g;
    int off           = which ? 64 : 128;
    const float* e = emb + n * 64;
    float acc = bias[c];
    #pragma unroll 8
    for (int k = 0; k < 64; ++k)
        acc = fmaf(e[k], W[(off + k) * 512 + c], acc);
    dst[n * 512 + c] = acc;
}

// w2P[node][a][d] = fw2[a][2*node+d]
__global__ void k_w2p(const float* __restrict__ fw2, float* __restrict__ w2P)
{
    int tid = blockIdx.x * 256 + threadIdx.x;   // grid 256 -> 65536
    int c = tid >> 9, a = tid & 511;            // c = 2*node+d
    int node = c >> 1, d = c & 1;
    w2P[(node * 512 + a) * 2 + d] = fw2[a * 128 + c];
}

// Fragment-linear f16 hi/lo splits (operand layout for mfma 16x16x32):
//  blocks [0,128):   fw1 (512x512), 16 ksteps x 32 ntg
//  blocks [128,160): fw0 FULL 128 rows, 4 ksteps x 32 ntg
//  blocks [160,288): gw1 (512x512)
//  blocks [288,304): gw2 (512x64)
//  blocks [304,306): embA: A-frags of embeddings (64x64), frag f = mtA*2+ks2
__global__ void k_splitw(const float* __restrict__ fw0, const float* __restrict__ fw1,
                         const float* __restrict__ gw1, const float* __restrict__ gw2,
                         const float* __restrict__ emb,
                         _Float16* __restrict__ fw0h, _Float16* __restrict__ fw0l,
                         _Float16* __restrict__ fw1h, _Float16* __restrict__ fw1l,
                         _Float16* __restrict__ gw1h, _Float16* __restrict__ gw1l,
                         _Float16* __restrict__ gw2h, _Float16* __restrict__ gw2l,
                         _Float16* __restrict__ embAh, _Float16* __restrict__ embAl)
{
    int tid = blockIdx.x * 256 + threadIdx.x;
    if (blockIdx.x < 128) {                       // fw1
        int l = tid & 63, grp = tid >> 6;
        int kstep = grp >> 5, ntg = grp & 31;
        #pragma unroll
        for (int j = 0; j < 8; ++j) {
            int k = kstep * 32 + (l >> 4) * 8 + j;
            int n = ntg * 16 + (l & 15);
            float v = fw1[k * 512 + n];
            _Float16 h = (_Float16)v;
            fw1h[tid * 8 + j] = h;
            fw1l[tid * 8 + j] = (_Float16)(v - (float)h);
        }
    } else if (blockIdx.x < 160) {                // fw0 full 128 rows
        int t2 = tid - 32768;
        int l = t2 & 63, grp = t2 >> 6;
        int kstep = grp >> 5, ntg = grp & 31;
        #pragma unroll
        for (int j = 0; j < 8; ++j) {
            int k = kstep * 32 + (l >> 4) * 8 + j;
            int n = ntg * 16 + (l & 15);
            float v = fw0[k * 512 + n];
            _Float16 h = (_Float16)v;
            fw0h[t2 * 8 + j] = h;
            fw0l[t2 * 8 + j] = (_Float16)(v - (float)h);
        }
    } else if (blockIdx.x < 288) {                // gw1
        int t4 = tid - 40960;
        int l = t4 & 63, grp = t4 >> 6;
        int kstep = grp >> 5, ntg = grp & 31;
        #pragma unroll
        for (int j = 0; j < 8; ++j) {
            int k = kstep * 32 + (l >> 4) * 8 + j;
            int n = ntg * 16 + (l & 15);
            float v = gw1[k * 512 + n];
            _Float16 h = (_Float16)v;
            gw1h[t4 * 8 + j] = h;
            gw1l[t4 * 8 + j] = (_Float16)(v - (float)h);
        }
    } else if (blockIdx.x < 304) {                // gw2
        int t3 = tid - 73728;
        int l = t3 & 63, grp = t3 >> 6;
        int kstep = grp >> 2, ntg = grp & 3;
        #pragma unroll
        for (int j = 0; j < 8; ++j) {
            int k = kstep * 32 + (l >> 4) * 8 + j;
            int n = ntg * 16 + (l & 15);
            float v = gw2[k * 64 + n];
            _Float16 h = (_Float16)v;
            gw2h[t3 * 8 + j] = h;
            gw2l[t3 * 8 + j] = (_Float16)(v - (float)h);
        }
    } else {                                      // embA A-frags
        int t5 = tid - 77824;                     // 0..511
        int l = t5 & 63, f = t5 >> 6;             // f = mtA*2 + ks2
        int mtA = f >> 1, ks2 = f & 1;
        #pragma unroll
        for (int j = 0; j < 8; ++j) {
            int m = mtA * 16 + (l & 15);
            int k = ks2 * 32 + (l >> 4) * 8 + j;
            float v = emb[m * 64 + k];
            _Float16 h = (_Float16)v;
            embAh[t5 * 8 + j] = h;
            embAl[t5 * 8 + j] = (_Float16)(v - (float)h);
        }
    }
}

// ---------------- k_gmlp: g-MLP on MFMA (unchanged) ----------------

__global__ __launch_bounds__(512, 2) void k_gmlp(
    const float* __restrict__ samples, const float* __restrict__ gw0,
    const float* __restrict__ base_g, const float* __restrict__ gb1,
    const float* __restrict__ gb2,
    const _Float16* __restrict__ gw1h, const _Float16* __restrict__ gw1l,
    const _Float16* __restrict__ gw2h, const _Float16* __restrict__ gw2l,
    float* __restrict__ emb_s)
{
    __shared__ __align__(16) unsigned char smem[81920];
    const int t = threadIdx.x, l = t & 63, wv = t >> 6;
    const int q = l >> 4, lr = l & 15;
    const int b = blockIdx.x;

    f32x4 zero4 = {0.f, 0.f, 0.f, 0.f};
    f32x4 acc[4][4];
    #pragma unroll
    for (int mt = 0; mt < 4; ++mt)
        #pragma unroll
        for (int nt = 0; nt < 4; ++nt) acc[mt][nt] = zero4;

    auto stage = [&](int kk, int bq) {
        #pragma unroll
        for (int it = 0; it < 4; ++it) {
            int n = it * 16 + (t >> 5);
            int c = kk * 32 + (t & 31);
            float s0 = samples[b * 128 + 2 * n];
            float s1 = samples[b * 128 + 2 * n + 1];
            float v = fmaf(s0, gw0[(2 * n) * 512 + c],
                      fmaf(s1, gw0[(2 * n + 1) * 512 + c], base_g[n * 512 + c]));
            v = leaky(v);
            int kl = t & 31;
            int sw = (((kl >> 2) ^ (n & 7)) << 2) | (kl & 3);
            *(uint32_t*)(smem + bq * 8192 + n * 128 + sw * 4) = packsplit(v);
        }
    };

    stage(0, 0);
    for (int kk = 0; kk < 16; ++kk) {
        const int pb = kk & 1;
        __syncthreads();
        if (kk < 15) stage(kk + 1, pb ^ 1);

        half8 Ah[4], Al[4];
        #pragma unroll
        for (int mt = 0; mt < 4; ++mt) {
            int row = mt * 16 + lr, f = row & 7;
            const unsigned char* rb = smem + pb * 8192 + row * 128;
            u32x4 w0 = *(const u32x4*)(rb + (((2 * q) ^ f) << 4));
            u32x4 w1 = *(const u32x4*)(rb + (((2 * q + 1) ^ f) << 4));
            unpackA(w0, w1, Ah[mt], Al[mt]);
        }
        #pragma unroll
        for (int nt = 0; nt < 4; ++nt) {
            int ntg = wv * 4 + nt;
            long boff = (long)((kk * 32 + ntg) * 64 + l) * 8;
            half8 Bh = *(const half8*)(gw1h + boff);
            half8 Bl = *(const half8*)(gw1l + boff);
            #pragma unroll
            for (int mt = 0; mt < 4; ++mt) {
                acc[mt][nt] = MFMA16(Ah[mt], Bh, acc[mt][nt]);
                acc[mt][nt] = MFMA16(Ah[mt], Bl, acc[mt][nt]);
                acc[mt][nt] = MFMA16(Al[mt], Bh, acc[mt][nt]);
            }
        }
    }

    const int mt2 = wv >> 1;
    f32x4 acc2[2] = {zero4, zero4};
    #pragma unroll
    for (int half = 0; half < 2; ++half) {
        __syncthreads();
        if ((wv >> 2) == half) {
            #pragma unroll
            for (int nt = 0; nt < 4; ++nt) {
                int col = wv * 64 + nt * 16 + lr;
                float bb = gb1[col];
                int ksl = (col >> 5) - half * 8;
                int kl = col & 31;
                #pragma unroll
                for (int mt = 0; mt < 4; ++mt)
                    #pragma unroll
                    for (int r = 0; r < 4; ++r) {
                        int row = mt * 16 + q * 4 + r;
                        float v = leaky(acc[mt][nt][r] + bb);
                        int sw = (((kl >> 2) ^ (row & 7)) << 2) | (kl & 3);
                        *(uint32_t*)(smem + 16384 + ksl * 8192 + row * 128 + sw * 4)
                            = packsplit(v);
                    }
            }
        }
        __syncthreads();
        #pragma unroll
        for (int ks = 0; ks < 8; ++ks) {
            int kstep = half * 8 + ks;
            int row = mt2 * 16 + lr, f = row & 7;
            const unsigned char* rb = smem + 16384 + ks * 8192 + row * 128;
            u32x4 w0 = *(const u32x4*)(rb + (((2 * q) ^ f) << 4));
            u32x4 w1 = *(const u32x4*)(rb + (((2 * q + 1) ^ f) << 4));
            half8 Ah2, Al2;
            unpackA(w0, w1, Ah2, Al2);
            #pragma unroll
            for (int nt = 0; nt < 2; ++nt) {
                int ntg = (wv & 1) * 2 + nt;
                long boff = (long)((kstep * 4 + ntg) * 64 + l) * 8;
                half8 Bh = *(const half8*)(gw2h + boff);
                half8 Bl = *(const half8*)(gw2l + boff);
                acc2[nt] = MFMA16(Ah2, Bh, acc2[nt]);
                acc2[nt] = MFMA16(Ah2, Bl, acc2[nt]);
                acc2[nt] = MFMA16(Al2, Bh, acc2[nt]);
            }
        }
    }
    #pragma unroll
    for (int nt = 0; nt < 2; ++nt) {
        int col = ((wv & 1) * 2 + nt) * 16 + lr;
        float bb = gb2[col];
        #pragma unroll
        for (int r = 0; r < 4; ++r) {
            int node = mt2 * 16 + q * 4 + r;
            emb_s[b * 4096 + node * 64 + col] = acc2[nt][r] + bb;
        }
    }
}

// ---------------- k_f7: fused f-MLP, f16 activations, x2 MFMA ----------------
// LDS (40 KB):
//   [0, 32768)     phase1: wadjT frags u32 [0,16K) + emb frags u32 [16K,32K);
//                  then h0 f16 plane [row 64][512 B] (granule swz);
//                  epilogue part overlay [0,4K)
//   [32768, 40960) A0 f16 plane [m 64][128 B], granule swz (8 granules/row)
// h0 granule swizzle: kgp = (kg & 16) | ((kg ^ row) & 15), kg = klocal>>3.
// A0 granule swizzle: kgp = (kg ^ (m & 7)) & 7, kg = kf>>3 (kf 0..63).

__global__ __launch_bounds__(512, 2) void k_f7(
    const float* __restrict__ graphs, const float* __restrict__ w,
    const float* __restrict__ emb_s,
    const float* __restrict__ fb0, const float* __restrict__ fb1,
    const float* __restrict__ w2P, const float* __restrict__ fb2,
    const _Float16* __restrict__ fw0h, const _Float16* __restrict__ fw0l,
    const _Float16* __restrict__ fw1h, const _Float16* __restrict__ fw1l,
    const _Float16* __restrict__ embAh,
    float* __restrict__ out)
{
    __shared__ __align__(16) unsigned char smem[40960];
    const int t = threadIdx.x, l = t & 63, wv = t >> 6;   // wv 0..7
    const int q = l >> 4, lr = l & 15;
    const int bid = blockIdx.x;
    const int m_blk = (bid & 7) * 256 + (bid >> 3);       // XCD-contiguous
    const int b = m_blk >> 3, g = m_blk & 7;

    // ---- Phase 1: split-f16 frags of wadjT and emb_s, direct from global ----
    {
        int mtW = wv >> 1, ksW = wv & 1;
        int jbase = ksW * 32 + (l >> 4) * 8;
        int col16 = mtW * 16 + (l & 15);
        #pragma unroll
        for (int j = 0; j < 8; ++j) {
            int jrow = jbase + j;
            float va = graphs[g * 4096 + jrow * 64 + col16] * w[jrow * 64 + col16];
            float vb = emb_s[b * 4096 + jrow * 64 + col16];
            *(uint32_t*)(smem + wv * 2048 + j * 256 + l * 4)         = packsplit(va);
            *(uint32_t*)(smem + 16384 + wv * 2048 + j * 256 + l * 4) = packsplit(vb);
        }
    }
    __syncthreads();

    // ---- Phase 2: aggr = wadjT @ emb_s via MFMA (x3) -> A0 f16 plane ----
    {
        #pragma unroll
        for (int cc2 = 0; cc2 < 2; ++cc2) {
            int combo = wv * 2 + cc2;
            int mtA = combo >> 2, ntA = combo & 3;
            f32x4 c = {0.f, 0.f, 0.f, 0.f};
            #pragma unroll
            for (int ks = 0; ks < 2; ++ks) {
                const unsigned char* ab = smem + (mtA * 2 + ks) * 2048 + l * 4;
                const unsigned char* bb = smem + 16384 + (ntA * 2 + ks) * 2048 + l * 4;
                u32x4 a0, a1, b0, b1;
                #pragma unroll
                for (int e = 0; e < 4; ++e) {
                    a0[e] = *(const uint32_t*)(ab + e * 256);
                    a1[e] = *(const uint32_t*)(ab + (4 + e) * 256);
                    b0[e] = *(const uint32_t*)(bb + e * 256);
                    b1[e] = *(const uint32_t*)(bb + (4 + e) * 256);
                }
                half8 Ah, Al, Bh, Bl;
                unpackA(a0, a1, Ah, Al);
                unpackA(b0, b1, Bh, Bl);
                c = MFMA16(Ah, Bh, c);
                c = MFMA16(Ah, Bl, c);
                c = MFMA16(Al, Bh, c);
            }
            #pragma unroll
            for (int r = 0; r < 4; ++r) {
                int node = mtA * 16 + (l >> 4) * 4 + r;
                int kf = ntA * 16 + (l & 15);
                int kgp = ((kf >> 3) ^ (node & 7)) & 7;
                *(_Float16*)(smem + 32768 + node * 128 + kgp * 16 + (kf & 7) * 2)
                    = (_Float16)c[r];
            }
        }
    }

    f32x4 zero4 = {0.f, 0.f, 0.f, 0.f};
    f32x4 acc1[4][4];
    #pragma unroll
    for (int mt = 0; mt < 4; ++mt)
        #pragma unroll
        for (int nt = 0; nt < 4; ++nt) acc1[mt][nt] = zero4;

    for (int sc = 0; sc < 2; ++sc) {
        __syncthreads();   // sc=0: A0 + frag reads done; sc=1: layer1 h0 reads done

        // ---- layer0 K=128 x2 (ks0,1: A0 plane; ks2,3: embA) + h0 write ----
        #pragma unroll
        for (int nt2 = 0; nt2 < 2; ++nt2) {
            int ntg = sc * 16 + wv * 2 + nt2;
            half8 B0h[4], B0l[4];
            #pragma unroll
            for (int ks = 0; ks < 4; ++ks) {
                long boff = (long)((ks * 32 + ntg) * 64 + l) * 8;
                B0h[ks] = *(const half8*)(fw0h + boff);
                B0l[ks] = *(const half8*)(fw0l + boff);
            }
            int klocal = wv * 32 + nt2 * 16 + lr;
            int kg = klocal >> 3;
            float b0v = fb0[sc * 256 + klocal];
            #pragma unroll
            for (int mt = 0; mt < 4; ++mt) {
                f32x4 c0 = zero4;
                #pragma unroll
                for (int ks = 0; ks < 2; ++ks) {
                    int m = mt * 16 + lr;
                    int kgA = ks * 4 + q;
                    int kgp = (kgA ^ (m & 7)) & 7;
                    half8 Ah = *(const half8*)(smem + 32768 + m * 128 + kgp * 16);
                    c0 = MFMA16(Ah, B0h[ks], c0);
                    c0 = MFMA16(Ah, B0l[ks], c0);
                }
                #pragma unroll
                for (int ks = 2; ks < 4; ++ks) {
                    long aoff = (long)((mt * 2 + (ks - 2)) * 64 + l) * 8;
                    half8 Ah = *(const half8*)(embAh + aoff);
                    c0 = MFMA16(Ah, B0h[ks], c0);
                    c0 = MFMA16(Ah, B0l[ks], c0);
                }
                #pragma unroll
                for (int r = 0; r < 4; ++r) {
                    int node = mt * 16 + q * 4 + r;
                    float v = leaky(c0[r] + b0v);
                    int kgp = (kg & 16) | ((kg ^ node) & 15);
                    int byte = node * 512 + kgp * 16 + (lr & 7) * 2;
                    *(_Float16*)(smem + byte) = (_Float16)v;
                }
            }
        }
        __syncthreads();   // h0 super-chunk ready

        // ---- layer1: 8 barrier-free K-steps, x2 MFMA ----
        #pragma unroll
        for (int kkl = 0; kkl < 8; ++kkl) {
            const int kk = sc * 8 + kkl;
            half8 Ah[4];
            #pragma unroll
            for (int mt = 0; mt < 4; ++mt) {
                int row = mt * 16 + lr;
                int kg = kkl * 4 + q;
                int kgp = (kg & 16) | ((kg ^ row) & 15);
                Ah[mt] = *(const half8*)(smem + row * 512 + kgp * 16);
            }
            #pragma unroll
            for (int nt = 0; nt < 4; ++nt) {
                int ntg = wv * 4 + nt;
                long boff = (long)((kk * 32 + ntg) * 64 + l) * 8;
                half8 Bh = *(const half8*)(fw1h + boff);
                half8 Bl = *(const half8*)(fw1l + boff);
                __builtin_amdgcn_s_setprio(1);
                #pragma unroll
                for (int mt = 0; mt < 4; ++mt) {
                    acc1[mt][nt] = MFMA16(Ah[mt], Bh, acc1[mt][nt]);
                    acc1[mt][nt] = MFMA16(Ah[mt], Bl, acc1[mt][nt]);
                }
                __builtin_amdgcn_s_setprio(0);
            }
        }
    }

    __syncthreads();   // layer1 reads done; safe to overlay part
    // ---- h1 bias/leaky + fused layer2 partial dots ----
    float* part = (float*)smem;   // [wv 8][node 64][d 2] = 4 KB
    #pragma unroll
    for (int mt = 0; mt < 4; ++mt) {
        float s0[4] = {0.f, 0.f, 0.f, 0.f}, s1[4] = {0.f, 0.f, 0.f, 0.f};
        #pragma unroll
        for (int nt = 0; nt < 4; ++nt) {
            int col = wv * 64 + nt * 16 + lr;
            float bb = fb1[col];
            #pragma unroll
            for (int r = 0; r < 4; ++r) {
                int node = mt * 16 + q * 4 + r;
                float h1 = leaky(acc1[mt][nt][r] + bb);
                float2 w2 = *(const float2*)(w2P + (((size_t)node * 512 + col) << 1));
                s0[r] = fmaf(h1, w2.x, s0[r]);
                s1[r] = fmaf(h1, w2.y, s1[r]);
            }
        }
        #pragma unroll
        for (int r = 0; r < 4; ++r) {
            s0[r] += __shfl_xor(s0[r], 1, 64); s0[r] += __shfl_xor(s0[r], 2, 64);
            s0[r] += __shfl_xor(s0[r], 4, 64); s0[r] += __shfl_xor(s0[r], 8, 64);
            s1[r] += __shfl_xor(s1[r], 1, 64); s1[r] += __shfl_xor(s1[r], 2, 64);
            s1[r] += __shfl_xor(s1[r], 4, 64); s1[r] += __shfl_xor(s1[r], 8, 64);
            if (lr == 0) {
                int node = mt * 16 + q * 4 + r;
                part[wv * 128 + node * 2 + 0] = s0[r];
                part[wv * 128 + node * 2 + 1] = s1[r];
            }
        }
    }
    __syncthreads();
    if (t < 128) {
        float s = 0.f;
        #pragma unroll
        for (int v8 = 0; v8 < 8; ++v8) s += part[v8 * 128 + t];
        out[m_blk * 128 + t] = s + fb2[t];
    }
}

// ---------------- launch ----------------

extern "C" void kernel_launch(void* const* d_in, const int* in_sizes, int n_in,
                              void* d_out, int out_size, void* d_ws, size_t ws_size,
                              hipStream_t stream)
{
    const float* samples    = (const float*)d_in[0];
    const float* graphs     = (const float*)d_in[1];
    const float* embeddings = (const float*)d_in[3];
    const float* w          = (const float*)d_in[4];
    const float* g_w0 = (const float*)d_in[5];
    const float* g_b0 = (const float*)d_in[6];
    const float* g_w1 = (const float*)d_in[7];
    const float* g_b1 = (const float*)d_in[8];
    const float* g_w2 = (const float*)d_in[9];
    const float* g_b2 = (const float*)d_in[10];
    const float* f_w0 = (const float*)d_in[11];
    const float* f_b0 = (const float*)d_in[12];
    const float* f_w1 = (const float*)d_in[13];
    const float* f_b1 = (const float*)d_in[14];
    const float* f_w2 = (const float*)d_in[15];
    const float* f_b2 = (const float*)d_in[16];
    float* out = (float*)d_out;

    float* ws     = (float*)d_ws;
    float* base_g = ws;                    // 32768 f
    float* base_f = ws + 32768;            // 32768 f (k_base output, unused by k_f7)
    float* w2P    = ws + 65536;            // 65536 f
    float* emb_s  = ws + 131072;           // 1048576 f
    _Float16* f16b = (_Float16*)(ws + 1179648);
    _Float16* fw1h  = f16b;                // 262144 h
    _Float16* fw1l  = f16b + 262144;
    _Float16* fw0h  = f16b + 524288;       // 65536 h (full 128 rows)
    _Float16* fw0l  = f16b + 589824;
    _Float16* gw1h  = f16b + 655360;       // 262144 h
    _Float16* gw1l  = f16b + 917504;
    _Float16* gw2h  = f16b + 1179648;      // 32768 h
    _Float16* gw2l  = f16b + 1212416;
    _Float16* embAh = f16b + 1245184;      // 4096 h
    _Float16* embAl = f16b + 1249280;      // end 1253376 h (~7.2 MB of ws)

    hipLaunchKernelGGL(k_base, dim3(256), dim3(256), 0, stream,
                       embeddings, g_w0, g_b0, f_w0, f_b0, base_g, base_f);
    hipLaunchKernelGGL(k_w2p, dim3(256), dim3(256), 0, stream, f_w2, w2P);
    hipLaunchKernelGGL(k_splitw, dim3(306), dim3(256), 0, stream,
                       f_w0, f_w1, g_w1, g_w2, embeddings,
                       fw0h, fw0l, fw1h, fw1l, gw1h, gw1l, gw2h, gw2l,
                       embAh, embAl);
    hipLaunchKernelGGL(k_gmlp, dim3(256), dim3(512), 0, stream,
                       samples, g_w0, base_g, g_b1, g_b2,
                       gw1h, gw1l, gw2h, gw2l, emb_s);
    hipLaunchKernelGGL(k_f7, dim3(2048), dim3(512), 0, stream,
                       graphs, w, emb_s, f_b0, f_b1, w2P, f_b2,
                       fw0h, fw0l, fw1h, fw1l, embAh, out);
}